// Round 1
// baseline (305.380 us; speedup 1.0000x reference)
//
#include <hip/hip_runtime.h>
#include <math.h>

// Problem constants (fixed by the reference setup_inputs)
static constexpr int A = 16384;
static constexpr int M = 32;
static constexpr int C = 15;
static constexpr int B = 2;

static constexpr double PI_D = 3.14159265358979323846;

// ---- workspace layout (bytes) ----
static constexpr size_t OFF_MD     = 0;                               // float[B][A][M]
static constexpr size_t SZ_MD      = (size_t)B * A * M * 4;
static constexpr size_t OFF_IOUMAX = OFF_MD + SZ_MD;                  // float[B][A]
static constexpr size_t OFF_IOUARG = OFF_IOUMAX + (size_t)B * A * 4;  // int[B][A]
static constexpr size_t OFF_POS    = OFF_IOUARG + (size_t)B * A * 4;  // int[B][A]
static constexpr size_t OFF_MAXPOS = OFF_POS + (size_t)B * A * 4;     // float[B][M]
static constexpr size_t OFF_ARGPOS = OFF_MAXPOS + (size_t)B * M * 4;  // int[B][M]
static constexpr size_t OFF_MWMAX  = OFF_ARGPOS + (size_t)B * M * 4;  // float[B][A]
static constexpr size_t OFF_NUMPOS = OFF_MWMAX + (size_t)B * A * 4;   // int[B]
static constexpr size_t OFF_SUMS   = OFF_NUMPOS + (size_t)B * 4;      // double[4]: cls[B], reg[B]
// total ~4.5 MB

// ---------- geometry helpers (all double) ----------
__device__ inline double aa_square_iou(double cx1, double cy1, double s1,
                                       double cx2, double cy2, double s2) {
    double ax0 = cx1 - s1, ay0 = cy1 - s1, ax1 = cx1 + s1, ay1 = cy1 + s1;
    double bx0 = cx2 - s2, by0 = cy2 - s2, bx1 = cx2 + s2, by1 = cy2 + s2;
    double lx = fmax(ax0, bx0), ly = fmax(ay0, by0);
    double rx = fmin(ax1, bx1), ry = fmin(ay1, by1);
    double w = fmax(rx - lx, 0.0), h = fmax(ry - ly, 0.0);
    double inter = w * h;
    double aa = (ax1 - ax0) * (ay1 - ay0);
    double ab = (bx1 - bx0) * (by1 - by0);
    return inter / (aa + ab - inter + 1e-8);
}

__device__ inline void rbox_corners1(double cx, double cy, double w, double h,
                                     double adeg, double* X, double* Y) {
    double t = adeg * (PI_D / 180.0);
    double c = cos(t), s = sin(t);
    const double lx[4] = {-0.5, 0.5, 0.5, -0.5};
    const double ly[4] = {-0.5, -0.5, 0.5, 0.5};
#pragma unroll
    for (int i = 0; i < 4; ++i) {
        double dx = w * lx[i], dy = h * ly[i];
        X[i] = cx + dx * c - dy * s;
        Y[i] = cy + dx * s + dy * c;
    }
}

// Sutherland–Hodgman clip of convex CCW quad A by convex CCW quad B; returns area.
__device__ double quad_inter_area(const double* AX, const double* AY,
                                  const double* BX, const double* BY) {
    double px[16], py[16], qx[16], qy[16];
    int n = 4;
#pragma unroll
    for (int i = 0; i < 4; ++i) { px[i] = AX[i]; py[i] = AY[i]; }
    for (int e = 0; e < 4; ++e) {
        double x1 = BX[e], y1 = BY[e];
        double x2 = BX[(e + 1) & 3], y2 = BY[(e + 1) & 3];
        double ex = x2 - x1, ey = y2 - y1;
        int m = 0;
        for (int k = 0; k < n; ++k) {
            double cx0 = px[k], cy0 = py[k];
            int k1 = (k + 1 == n) ? 0 : k + 1;
            double cx1 = px[k1], cy1 = py[k1];
            double d0 = ex * (cy0 - y1) - ey * (cx0 - x1);
            double d1 = ex * (cy1 - y1) - ey * (cx1 - x1);
            bool in0 = d0 >= 0.0, in1 = d1 >= 0.0;
            if (in0) { qx[m] = cx0; qy[m] = cy0; ++m; }
            if (in0 != in1) {
                double tt = d0 / (d0 - d1);
                qx[m] = cx0 + tt * (cx1 - cx0);
                qy[m] = cy0 + tt * (cy1 - cy0);
                ++m;
            }
        }
        n = m;
        if (n == 0) break;
        for (int k = 0; k < n; ++k) { px[k] = qx[k]; py[k] = qy[k]; }
    }
    if (n < 3) return 0.0;
    double area = 0.0;
    for (int k = 0; k < n; ++k) {
        int k1 = (k + 1 == n) ? 0 : k + 1;
        area += px[k] * py[k1] - px[k1] * py[k];
    }
    return 0.5 * fabs(area);
}

// rotated IoU of one anchor-like box vs one gt box, gated on AA-square IoU >= 0.1
__device__ inline double rot_iou(const float* bA, const float* bG) {
    double cxa = bA[0], cya = bA[1], wa = bA[2], ha = bA[3], aa = bA[4];
    double cxg = bG[0], cyg = bG[1], wg = bG[2], hg = bG[3], ag = bG[4];
    double sa = 0.5 * fmax(wa, ha);
    double sg = 0.5 * fmax(wg, hg);
    double ind = aa_square_iou(cxa, cya, sa, cxg, cyg, sg);
    if (!(ind >= 0.1)) return 0.0;
    double AX[4], AY[4], BX[4], BY[4];
    rbox_corners1(cxa, cya, wa, ha, aa, AX, AY);
    rbox_corners1(cxg, cyg, wg, hg, ag, BX, BY);
    double inter = quad_inter_area(AX, AY, BX, BY);
    double areaA = wa * ha, areaG = wg * hg;
    return inter / (areaA + areaG - inter + 1e-8);
}

// ---------- kernels ----------
__global__ void k_pairs(const float* __restrict__ anc, const float* __restrict__ ranc,
                        const float* __restrict__ ann, float* __restrict__ md,
                        double* __restrict__ sums) {
    int t = blockIdx.x * 256 + threadIdx.x;
    if (t < 4) sums[t] = 0.0;  // zero cls/reg accumulators
    if (t >= B * A * M) return;
    int b = t / (A * M);
    int rem = t - b * (A * M);
    int a = rem / M;
    int m = rem - a * M;
    const float* pa = anc + ((size_t)(b * A + a)) * 5;
    const float* pr = ranc + ((size_t)(b * A + a)) * 5;
    const float* pg = ann + ((size_t)(b * M + m)) * 6;
    double ov_bf = rot_iou(pa, pg);
    double ov_af = rot_iou(pr, pg);
    // md = |BF*ov_bf + AF*ov_af - |ov_af - ov_bf|^VAR|, BF=1, AF=0.5, VAR=1
    double mdv = fabs(ov_bf + 0.5 * ov_af - fabs(ov_af - ov_bf));
    md[t] = (float)mdv;
}

__global__ void k_anchor(const float* __restrict__ md, float* __restrict__ iou_max,
                         int* __restrict__ iou_arg, int* __restrict__ pos) {
    int t = blockIdx.x * 256 + threadIdx.x;
    if (t >= B * A) return;
    const float* row = md + (size_t)t * M;
    float best = row[0];
    int bi = 0;
#pragma unroll
    for (int m = 1; m < M; ++m) {
        float v = row[m];
        if (v > best) { best = v; bi = m; }  // strict > keeps first index (JAX argmax)
    }
    iou_max[t] = best;
    iou_arg[t] = bi;
    pos[t] = (best >= 0.5f) ? 1 : 0;
}

__device__ inline unsigned long long pack_key(float v, int idx) {
    return ((unsigned long long)__float_as_uint(v) << 32) |
           (unsigned long long)(0xFFFFFFFFu - (unsigned)idx);
}

// per-gt max over all anchors; force-assign pos when max_gt < 0.5
__global__ void k_gtforce(const float* __restrict__ md, int* __restrict__ pos) {
    int m = blockIdx.x, b = blockIdx.y, tid = threadIdx.x;
    unsigned long long key = 0ull;
    for (int a = tid; a < A; a += 256) {
        float v = md[((size_t)(b * A + a)) * M + m];
        unsigned long long k = pack_key(v, a);
        if (k > key) key = k;
    }
    __shared__ unsigned long long sk[256];
    sk[tid] = key;
    __syncthreads();
    for (int s = 128; s > 0; s >>= 1) {
        if (tid < s && sk[tid + s] > sk[tid]) sk[tid] = sk[tid + s];
        __syncthreads();
    }
    if (tid == 0) {
        float mx = __uint_as_float((unsigned)(sk[0] >> 32));
        int arg = (int)(0xFFFFFFFFu - (unsigned)(sk[0] & 0xFFFFFFFFull));
        if (mx < 0.5f) atomicOr(&pos[b * A + arg], 1);
    }
}

// per-gt max over POS anchors (+ first-index argmax); block (m==0) also counts num_pos
__global__ void k_posmax(const float* __restrict__ md, const int* __restrict__ pos,
                         float* __restrict__ max_pos, int* __restrict__ arg_pos,
                         int* __restrict__ num_pos) {
    int m = blockIdx.x, b = blockIdx.y, tid = threadIdx.x;
    unsigned long long key = 0ull;
    int cnt = 0;
    for (int a = tid; a < A; a += 256) {
        int p = pos[b * A + a];
        if (m == 0) cnt += p;
        if (p) {
            float v = md[((size_t)(b * A + a)) * M + m];
            unsigned long long k = pack_key(v, a);
            if (k > key) key = k;
        }
    }
    __shared__ unsigned long long sk[256];
    __shared__ int sc[256];
    sk[tid] = key;
    sc[tid] = cnt;
    __syncthreads();
    for (int s = 128; s > 0; s >>= 1) {
        if (tid < s) {
            if (sk[tid + s] > sk[tid]) sk[tid] = sk[tid + s];
            sc[tid] += sc[tid + s];
        }
        __syncthreads();
    }
    if (tid == 0) {
        if (sk[0] == 0ull) {
            max_pos[b * M + m] = 0.0f;
            arg_pos[b * M + m] = -1;
        } else {
            max_pos[b * M + m] = __uint_as_float((unsigned)(sk[0] >> 32));
            arg_pos[b * M + m] = (int)(0xFFFFFFFFu - (unsigned)(sk[0] & 0xFFFFFFFFull));
        }
        if (m == 0) num_pos[b] = sc[0];
    }
}

__global__ void k_mwmax(const float* __restrict__ md, const int* __restrict__ pos,
                        const float* __restrict__ max_pos, const int* __restrict__ arg_pos,
                        float* __restrict__ mw_max) {
    int t = blockIdx.x * 256 + threadIdx.x;
    if (t >= B * A) return;
    int b = t / A;
    int a = t - b * A;
    const float* row = md + (size_t)t * M;
    int p = pos[t];
    float mw = -INFINITY;
#pragma unroll
    for (int m = 0; m < M; ++m) {
        float v = row[m];
        bool pm = (p && v >= 0.5f) || (a == arg_pos[b * M + m]);
        float val = pm ? (1.0f - max_pos[b * M + m] + v) : (v + v);
        mw = fmaxf(mw, val);
    }
    mw_max[t] = mw;
}

__global__ void k_loss(const float* __restrict__ cls_in, const float* __restrict__ reg_in,
                       const float* __restrict__ anc, const float* __restrict__ ann,
                       const float* __restrict__ iou_max, const int* __restrict__ iou_arg,
                       const int* __restrict__ pos, const float* __restrict__ mw_max,
                       double* __restrict__ sums) {
    int b = blockIdx.y;
    int tid = threadIdx.x;
    int a = blockIdx.x * 256 + tid;
    double csum = 0.0, rsum = 0.0;
    if (a < A) {
        int t = b * A + a;
        float imax = iou_max[t];
        int iarg = iou_arg[t];
        int p = pos[t];
        double mw = (double)mw_max[t];
        const float* g = ann + ((size_t)(b * M + iarg)) * 6;
        int lab = (int)g[5];
        const float* cp = cls_in + (size_t)t * C;
#pragma unroll
        for (int c = 0; c < C; ++c) {
            double x = (double)cp[c];
            x = fmin(fmax(x, 1e-4), 1.0 - 1e-4);
            double tgt;
            if (p) tgt = (c == lab) ? 1.0 : 0.0;
            else   tgt = (imax < 0.4f) ? 0.0 : -1.0;
            if (tgt >= 0.0) {
                bool one = (tgt == 1.0);
                double af = one ? 0.25 : 0.75;
                double q = one ? (1.0 - x) : x;
                double fw = af * q * q;
                double bce = one ? -log(x + 1e-6) : -log(1.0 - x + 1e-6);
                double sw = one ? (mw + 1.0) : 1.0;
                csum += fw * bce * sw;
            }
        }
        if (p) {
            const float* pa = anc + (size_t)t * 5;
            double gw = fmax((double)g[2], 1.0);
            double gh = fmax((double)g[3], 1.0);
            double rt0 = ((double)g[0] - (double)pa[0]) / (double)pa[2];
            double rt1 = ((double)g[1] - (double)pa[1]) / (double)pa[3];
            double rt2 = log(gw / (double)pa[2]);
            double rt3 = log(gh / (double)pa[3]);
            double rt4 = tan((double)g[4] * (PI_D / 180.0)) - tan((double)pa[4] * (PI_D / 180.0));
            double rt[5] = {rt0, rt1, rt2, rt3, rt4};
            const float* rg = reg_in + (size_t)t * 5;
#pragma unroll
            for (int k = 0; k < 5; ++k) {
                double d = fabs((double)rg[k] - rt[k]);
                double s = (d < (1.0 / 9.0)) ? (0.5 * d * d * 9.0) : (d - 0.5 / 9.0);
                rsum += s * mw;
            }
        }
    }
    __shared__ double scs[256];
    __shared__ double srs[256];
    scs[tid] = csum;
    srs[tid] = rsum;
    __syncthreads();
    for (int s = 128; s > 0; s >>= 1) {
        if (tid < s) { scs[tid] += scs[tid + s]; srs[tid] += srs[tid + s]; }
        __syncthreads();
    }
    if (tid == 0) {
        atomicAdd(&sums[b], scs[0]);
        atomicAdd(&sums[2 + b], srs[0]);
    }
}

__global__ void k_final(const double* __restrict__ sums, const int* __restrict__ num_pos,
                        float* __restrict__ out) {
    if (blockIdx.x == 0 && threadIdx.x == 0) {
        double lc = 0.0, lr = 0.0;
        for (int b = 0; b < B; ++b) {
            double npd = (double)num_pos[b];
            lc += sums[b] / fmax(npd, 1.0);
            int denom = num_pos[b] * 5;
            if (denom < 1) denom = 1;
            lr += (num_pos[b] > 0) ? (sums[2 + b] / (double)denom) : 0.0;
        }
        out[0] = (float)(lc / (double)B);
        out[1] = (float)(lr / (double)B);
    }
}

extern "C" void kernel_launch(void* const* d_in, const int* in_sizes, int n_in,
                              void* d_out, int out_size, void* d_ws, size_t ws_size,
                              hipStream_t stream) {
    const float* cls  = (const float*)d_in[0];  // (B, A, C)
    const float* reg  = (const float*)d_in[1];  // (B, A, 5)
    const float* anc  = (const float*)d_in[2];  // (B, A, 5)
    const float* ranc = (const float*)d_in[3];  // (B, A, 5)
    const float* ann  = (const float*)d_in[4];  // (B, M, 6)
    float* out = (float*)d_out;

    char* ws = (char*)d_ws;
    float* md       = (float*)(ws + OFF_MD);
    float* iou_max  = (float*)(ws + OFF_IOUMAX);
    int*   iou_arg  = (int*)(ws + OFF_IOUARG);
    int*   pos      = (int*)(ws + OFF_POS);
    float* max_pos  = (float*)(ws + OFF_MAXPOS);
    int*   arg_pos  = (int*)(ws + OFF_ARGPOS);
    float* mw_max   = (float*)(ws + OFF_MWMAX);
    int*   num_pos  = (int*)(ws + OFF_NUMPOS);
    double* sums    = (double*)(ws + OFF_SUMS);

    (void)in_sizes; (void)n_in; (void)out_size; (void)ws_size;

    k_pairs<<<(B * A * M + 255) / 256, 256, 0, stream>>>(anc, ranc, ann, md, sums);
    k_anchor<<<(B * A + 255) / 256, 256, 0, stream>>>(md, iou_max, iou_arg, pos);
    k_gtforce<<<dim3(M, B), 256, 0, stream>>>(md, pos);
    k_posmax<<<dim3(M, B), 256, 0, stream>>>(md, pos, max_pos, arg_pos, num_pos);
    k_mwmax<<<(B * A + 255) / 256, 256, 0, stream>>>(md, pos, max_pos, arg_pos, mw_max);
    k_loss<<<dim3((A + 255) / 256, B), 256, 0, stream>>>(cls, reg, anc, ann, iou_max,
                                                         iou_arg, pos, mw_max, sums);
    k_final<<<1, 64, 0, stream>>>(sums, num_pos, out);
}

// Round 4
// 189.764 us; speedup vs baseline: 1.6093x; 1.6093x over previous
//
#include <hip/hip_runtime.h>
#include <math.h>

// Problem constants (fixed by the reference setup_inputs)
static constexpr int A = 16384;
static constexpr int M = 32;
static constexpr int C = 15;
static constexpr int B = 2;

static constexpr double PI_D = 3.14159265358979323846;

// ---- workspace layout (bytes) ----
static constexpr size_t OFF_MD     = 0;                               // float[B][A][M]
static constexpr size_t SZ_MD      = (size_t)B * A * M * 4;
static constexpr size_t OFF_IOUMAX = OFF_MD + SZ_MD;                  // float[B][A]
static constexpr size_t OFF_IOUARG = OFF_IOUMAX + (size_t)B * A * 4;  // int[B][A]
static constexpr size_t OFF_POS    = OFF_IOUARG + (size_t)B * A * 4;  // int[B][A]
static constexpr size_t OFF_MAXPOS = OFF_POS + (size_t)B * A * 4;     // float[B][M]
static constexpr size_t OFF_ARGPOS = OFF_MAXPOS + (size_t)B * M * 4;  // int[B][M]
static constexpr size_t OFF_NUMPOS = OFF_ARGPOS + (size_t)B * M * 4;  // int[B]
static constexpr size_t OFF_SUMS   = OFF_NUMPOS + (size_t)B * 4 + 56; // double[4] (8B aligned)

// ---------- geometry helpers (all double, fully register-resident) ----------
__device__ inline double aa_square_iou(double cx1, double cy1, double s1,
                                       double cx2, double cy2, double s2) {
    double lx = fmax(cx1 - s1, cx2 - s2), ly = fmax(cy1 - s1, cy2 - s2);
    double rx = fmin(cx1 + s1, cx2 + s2), ry = fmin(cy1 + s1, cy2 + s2);
    double w = fmax(rx - lx, 0.0), h = fmax(ry - ly, 0.0);
    double inter = w * h;
    double aa = (2.0 * s1) * (2.0 * s1);
    double ab = (2.0 * s2) * (2.0 * s2);
    return inter / (aa + ab - inter + 1e-8);
}

__device__ inline void rbox_corners1(double cx, double cy, double w, double h,
                                     double adeg, double* X, double* Y) {
    double t = adeg * (PI_D / 180.0);
    double c = cos(t), s = sin(t);
    const double lx[4] = {-0.5, 0.5, 0.5, -0.5};
    const double ly[4] = {-0.5, -0.5, 0.5, 0.5};
#pragma unroll
    for (int i = 0; i < 4; ++i) {
        double dx = w * lx[i], dy = h * ly[i];
        X[i] = cx + dx * c - dy * s;
        Y[i] = cy + dx * s + dy * c;
    }
}

// Sum of cross(a,b) over the sub-segments of P's edges lying inside convex CCW
// quad Q (interval clipping — no arrays, no scatter). The closed boundary of
// P∩Q is exactly {P-edge parts inside Q} ∪ {Q-edge parts inside P}, and
// ∮ x dy − y dx over it equals 2·area regardless of arc enumeration order.
__device__ inline double edges_in_quad_cross_sum(const double* PX, const double* PY,
                                                 const double* QX, const double* QY) {
    double s = 0.0;
#pragma unroll
    for (int k = 0; k < 4; ++k) {
        double x0 = PX[k], y0 = PY[k];
        double x1 = PX[(k + 1) & 3], y1 = PY[(k + 1) & 3];
        double ex = x1 - x0, ey = y1 - y0;
        double t0 = 0.0, t1 = 1.0;
        bool empty = false;
#pragma unroll
        for (int e = 0; e < 4; ++e) {
            double qx0 = QX[e], qy0 = QY[e];
            double qex = QX[(e + 1) & 3] - qx0;
            double qey = QY[(e + 1) & 3] - qy0;
            double d0 = qex * (y0 - qy0) - qey * (x0 - qx0);  // >=0 inside (CCW)
            double d1 = qex * (y1 - qy0) - qey * (x1 - qx0);
            if (d0 < 0.0 && d1 < 0.0) empty = true;
            else if (d0 < 0.0) t0 = fmax(t0, d0 / (d0 - d1));
            else if (d1 < 0.0) t1 = fmin(t1, d0 / (d0 - d1));
        }
        if (!empty && t1 > t0) {
            double ax = x0 + t0 * ex, ay = y0 + t0 * ey;
            double bx = x0 + t1 * ex, by = y0 + t1 * ey;
            s += ax * by - ay * bx;
        }
    }
    return s;
}

__device__ inline double quad_inter_area(const double* AX, const double* AY,
                                         const double* BX, const double* BY) {
    double s = edges_in_quad_cross_sum(AX, AY, BX, BY) +
               edges_in_quad_cross_sum(BX, BY, AX, AY);
    return 0.5 * fabs(s);
}

__device__ inline unsigned long long pack_key(float v, unsigned inv_idx) {
    return ((unsigned long long)__float_as_uint(v) << 32) | (unsigned long long)inv_idx;
}

// ---------- kernels ----------
// One thread per (b, a, m) pair; m is the fast (lane) index so each 32-lane
// group holds one anchor's full md row -> fused row max/argmax via shfl.
__global__ void k_pairs(const float* __restrict__ anc, const float* __restrict__ ranc,
                        const float* __restrict__ ann, float* __restrict__ md,
                        float* __restrict__ iou_max, int* __restrict__ iou_arg,
                        int* __restrict__ pos, double* __restrict__ sums) {
    int t = blockIdx.x * 256 + threadIdx.x;
    if (t < 4) sums[t] = 0.0;
    int m = t & (M - 1);
    int a = (t >> 5) & (A - 1);
    int b = t >> 19;

    const float* pa = anc + ((size_t)(b * A + a)) * 5;
    const float* pr = ranc + ((size_t)(b * A + a)) * 5;
    const float* pg = ann + ((size_t)(b * M + m)) * 6;

    double cxg = pg[0], cyg = pg[1], wg = pg[2], hg = pg[3], ag = pg[4];
    double sg = 0.5 * fmax(wg, hg);

    double cxa = pa[0], cya = pa[1], wa = pa[2], ha = pa[3], aa = pa[4];
    double cxr = pr[0], cyr = pr[1], wr = pr[2], hr = pr[3], ar = pr[4];

    double ind_bf = aa_square_iou(cxa, cya, 0.5 * fmax(wa, ha), cxg, cyg, sg);
    double ind_af = aa_square_iou(cxr, cyr, 0.5 * fmax(wr, hr), cxg, cyg, sg);

    double ov_bf = 0.0, ov_af = 0.0;
    if (ind_bf >= 0.1 || ind_af >= 0.1) {
        double GX[4], GY[4];
        rbox_corners1(cxg, cyg, wg, hg, ag, GX, GY);
        double areaG = wg * hg;
        if (ind_bf >= 0.1) {
            double X[4], Y[4];
            rbox_corners1(cxa, cya, wa, ha, aa, X, Y);
            double inter = quad_inter_area(X, Y, GX, GY);
            ov_bf = inter / (wa * ha + areaG - inter + 1e-8);
        }
        if (ind_af >= 0.1) {
            double X[4], Y[4];
            rbox_corners1(cxr, cyr, wr, hr, ar, X, Y);
            double inter = quad_inter_area(X, Y, GX, GY);
            ov_af = inter / (wr * hr + areaG - inter + 1e-8);
        }
    }
    // md = |BF*ov_bf + AF*ov_af - |ov_af - ov_bf|^VAR|, BF=1, AF=0.5, VAR=1
    float mdv = (float)fabs(ov_bf + 0.5 * ov_af - fabs(ov_af - ov_bf));
    md[t] = mdv;

    // fused per-anchor row max + first-index argmax (width-32 butterfly)
    unsigned long long key = pack_key(mdv, (unsigned)(31 - m));
#pragma unroll
    for (int off = 16; off > 0; off >>= 1) {
        unsigned long long other = __shfl_xor(key, off, 32);
        if (other > key) key = other;
    }
    if (m == 0) {
        float best = __uint_as_float((unsigned)(key >> 32));
        int bi = 31 - (int)(key & 0xFFFFFFFFull);
        int idx = b * A + a;
        iou_max[idx] = best;
        iou_arg[idx] = bi;
        pos[idx] = (best >= 0.5f) ? 1 : 0;
    }
}

// per-gt max over all anchors; force-assign pos when max_gt < 0.5
__global__ void k_gtforce(const float* __restrict__ md, int* __restrict__ pos) {
    int m = blockIdx.x, b = blockIdx.y, tid = threadIdx.x;
    unsigned long long key = 0ull;
    for (int a = tid; a < A; a += 256) {
        float v = md[((size_t)(b * A + a)) * M + m];
        unsigned long long k = pack_key(v, 0xFFFFFFFFu - (unsigned)a);
        if (k > key) key = k;
    }
    __shared__ unsigned long long sk[256];
    sk[tid] = key;
    __syncthreads();
    for (int s = 128; s > 0; s >>= 1) {
        if (tid < s && sk[tid + s] > sk[tid]) sk[tid] = sk[tid + s];
        __syncthreads();
    }
    if (tid == 0) {
        float mx = __uint_as_float((unsigned)(sk[0] >> 32));
        int arg = (int)(0xFFFFFFFFu - (unsigned)(sk[0] & 0xFFFFFFFFull));
        if (mx < 0.5f) atomicOr(&pos[b * A + arg], 1);
    }
}

// per-gt max over POS anchors (+ first-index argmax); m==0 block counts num_pos
__global__ void k_posmax(const float* __restrict__ md, const int* __restrict__ pos,
                         float* __restrict__ max_pos, int* __restrict__ arg_pos,
                         int* __restrict__ num_pos) {
    int m = blockIdx.x, b = blockIdx.y, tid = threadIdx.x;
    unsigned long long key = 0ull;
    int cnt = 0;
    for (int a = tid; a < A; a += 256) {
        int p = pos[b * A + a];
        if (m == 0) cnt += p;
        if (p) {
            float v = md[((size_t)(b * A + a)) * M + m];
            unsigned long long k = pack_key(v, 0xFFFFFFFFu - (unsigned)a);
            if (k > key) key = k;
        }
    }
    __shared__ unsigned long long sk[256];
    __shared__ int sc[256];
    sk[tid] = key;
    sc[tid] = cnt;
    __syncthreads();
    for (int s = 128; s > 0; s >>= 1) {
        if (tid < s) {
            if (sk[tid + s] > sk[tid]) sk[tid] = sk[tid + s];
            sc[tid] += sc[tid + s];
        }
        __syncthreads();
    }
    if (tid == 0) {
        if (sk[0] == 0ull) {
            max_pos[b * M + m] = 0.0f;
            arg_pos[b * M + m] = -1;
        } else {
            max_pos[b * M + m] = __uint_as_float((unsigned)(sk[0] >> 32));
            arg_pos[b * M + m] = (int)(0xFFFFFFFFu - (unsigned)(sk[0] & 0xFFFFFFFFull));
        }
        if (m == 0) num_pos[b] = sc[0];
    }
}

// fused: per-anchor mw_max recompute + focal cls loss + smooth-L1 reg loss
__global__ void k_loss(const float* __restrict__ cls_in, const float* __restrict__ reg_in,
                       const float* __restrict__ anc, const float* __restrict__ ann,
                       const float* __restrict__ md,
                       const float* __restrict__ iou_max, const int* __restrict__ iou_arg,
                       const int* __restrict__ pos,
                       const float* __restrict__ max_pos, const int* __restrict__ arg_pos,
                       double* __restrict__ sums) {
    int b = blockIdx.y;
    int tid = threadIdx.x;
    int a = blockIdx.x * 256 + tid;

    __shared__ float s_maxpos[M];
    __shared__ int s_argpos[M];
    if (tid < M) {
        s_maxpos[tid] = max_pos[b * M + tid];
        s_argpos[tid] = arg_pos[b * M + tid];
    }
    __syncthreads();

    double csum = 0.0, rsum = 0.0;
    if (a < A) {
        int t = b * A + a;
        float imax = iou_max[t];
        int iarg = iou_arg[t];
        int p = pos[t];

        // mw_max
        const float* row = md + (size_t)t * M;
        float mwf = -INFINITY;
#pragma unroll
        for (int m = 0; m < M; ++m) {
            float v = row[m];
            bool pm = (p && v >= 0.5f) || (a == s_argpos[m]);
            float val = pm ? (1.0f - s_maxpos[m] + v) : (v + v);
            mwf = fmaxf(mwf, val);
        }
        double mw = (double)mwf;

        const float* g = ann + ((size_t)(b * M + iarg)) * 6;
        int lab = (int)g[5];
        const float* cp = cls_in + (size_t)t * C;
#pragma unroll
        for (int c = 0; c < C; ++c) {
            double x = (double)cp[c];
            x = fmin(fmax(x, 1e-4), 1.0 - 1e-4);
            double tgt;
            if (p) tgt = (c == lab) ? 1.0 : 0.0;
            else   tgt = (imax < 0.4f) ? 0.0 : -1.0;
            if (tgt >= 0.0) {
                bool one = (tgt == 1.0);
                double af = one ? 0.25 : 0.75;
                double q = one ? (1.0 - x) : x;
                double fw = af * q * q;
                double bce = one ? -log(x + 1e-6) : -log(1.0 - x + 1e-6);
                double sw = one ? (mw + 1.0) : 1.0;
                csum += fw * bce * sw;
            }
        }
        if (p) {
            const float* pa = anc + (size_t)t * 5;
            double gw = fmax((double)g[2], 1.0);
            double gh = fmax((double)g[3], 1.0);
            double rt0 = ((double)g[0] - (double)pa[0]) / (double)pa[2];
            double rt1 = ((double)g[1] - (double)pa[1]) / (double)pa[3];
            double rt2 = log(gw / (double)pa[2]);
            double rt3 = log(gh / (double)pa[3]);
            double rt4 = tan((double)g[4] * (PI_D / 180.0)) - tan((double)pa[4] * (PI_D / 180.0));
            double rt[5] = {rt0, rt1, rt2, rt3, rt4};
            const float* rg = reg_in + (size_t)t * 5;
#pragma unroll
            for (int k = 0; k < 5; ++k) {
                double d = fabs((double)rg[k] - rt[k]);
                double s = (d < (1.0 / 9.0)) ? (0.5 * d * d * 9.0) : (d - 0.5 / 9.0);
                rsum += s * mw;
            }
        }
    }
    __shared__ double scs[256];
    __shared__ double srs[256];
    scs[tid] = csum;
    srs[tid] = rsum;
    __syncthreads();
    for (int s = 128; s > 0; s >>= 1) {
        if (tid < s) { scs[tid] += scs[tid + s]; srs[tid] += srs[tid + s]; }
        __syncthreads();
    }
    if (tid == 0) {
        atomicAdd(&sums[b], scs[0]);
        atomicAdd(&sums[2 + b], srs[0]);
    }
}

__global__ void k_final(const double* __restrict__ sums, const int* __restrict__ num_pos,
                        float* __restrict__ out) {
    if (blockIdx.x == 0 && threadIdx.x == 0) {
        double lc = 0.0, lr = 0.0;
        for (int b = 0; b < B; ++b) {
            double npd = (double)num_pos[b];
            lc += sums[b] / fmax(npd, 1.0);
            int denom = num_pos[b] * 5;
            if (denom < 1) denom = 1;
            lr += (num_pos[b] > 0) ? (sums[2 + b] / (double)denom) : 0.0;
        }
        out[0] = (float)(lc / (double)B);
        out[1] = (float)(lr / (double)B);
    }
}

extern "C" void kernel_launch(void* const* d_in, const int* in_sizes, int n_in,
                              void* d_out, int out_size, void* d_ws, size_t ws_size,
                              hipStream_t stream) {
    const float* cls  = (const float*)d_in[0];  // (B, A, C)
    const float* reg  = (const float*)d_in[1];  // (B, A, 5)
    const float* anc  = (const float*)d_in[2];  // (B, A, 5)
    const float* ranc = (const float*)d_in[3];  // (B, A, 5)
    const float* ann  = (const float*)d_in[4];  // (B, M, 6)
    float* out = (float*)d_out;

    char* ws = (char*)d_ws;
    float* md       = (float*)(ws + OFF_MD);
    float* iou_max  = (float*)(ws + OFF_IOUMAX);
    int*   iou_arg  = (int*)(ws + OFF_IOUARG);
    int*   pos      = (int*)(ws + OFF_POS);
    float* max_pos  = (float*)(ws + OFF_MAXPOS);
    int*   arg_pos  = (int*)(ws + OFF_ARGPOS);
    int*   num_pos  = (int*)(ws + OFF_NUMPOS);
    double* sums    = (double*)(ws + OFF_SUMS);

    (void)in_sizes; (void)n_in; (void)out_size; (void)ws_size;

    k_pairs<<<(B * A * M) / 256, 256, 0, stream>>>(anc, ranc, ann, md,
                                                   iou_max, iou_arg, pos, sums);
    k_gtforce<<<dim3(M, B), 256, 0, stream>>>(md, pos);
    k_posmax<<<dim3(M, B), 256, 0, stream>>>(md, pos, max_pos, arg_pos, num_pos);
    k_loss<<<dim3((A + 255) / 256, B), 256, 0, stream>>>(cls, reg, anc, ann, md,
                                                         iou_max, iou_arg, pos,
                                                         max_pos, arg_pos, sums);
    k_final<<<1, 64, 0, stream>>>(sums, num_pos, out);
}